// Round 5
// baseline (197.237 us; speedup 1.0000x reference)
//
#include <hip/hip_runtime.h>
#include <cstddef>

// Problem constants (n=2, c=128, h=w=96, hid=256, P=5, heads=8, d_k=16)
constexpr int Cc = 128;
constexpr int Hh = 96;
constexpr int Ww = 96;
constexpr int HW = Hh * Ww;      // 9216 pixels per image
constexpr int Nn = 2;

typedef __attribute__((ext_vector_type(2))) _Float16 f16x2;
typedef __attribute__((ext_vector_type(4))) _Float16 f16x4;
typedef __attribute__((ext_vector_type(8))) _Float16 f16x8;
typedef __attribute__((ext_vector_type(4))) float f32x4;

__device__ __forceinline__ float fdot2(f16x2 a, f16x2 b, float c) {
#if defined(__has_builtin) && __has_builtin(__builtin_amdgcn_fdot2)
    return __builtin_amdgcn_fdot2(a, b, c, false);
#else
    return (float)a[0] * (float)b[0] + (float)a[1] * (float)b[1] + c;
#endif
}

// ---------------------------------------------------------------------------
// Weight fp32 -> f16 converter (all 6 matrices into one packed buffer).
// Layout: wq @0, wk @16384, wv @32768, wfc @49152, w1 @65536, w2 @98304.
// ---------------------------------------------------------------------------
__global__ void __launch_bounds__(256)
wcvt_k(const float* __restrict__ wq, const float* __restrict__ wk,
       const float* __restrict__ wv, const float* __restrict__ wfc,
       const float* __restrict__ w1, const float* __restrict__ w2,
       _Float16* __restrict__ dst)
{
    const int i = (blockIdx.x * 256 + threadIdx.x) * 4;
    const float* src; int off;
    if (i < 16384)      { src = wq;  off = i; }
    else if (i < 32768) { src = wk;  off = i - 16384; }
    else if (i < 49152) { src = wv;  off = i - 32768; }
    else if (i < 65536) { src = wfc; off = i - 49152; }
    else if (i < 98304) { src = w1;  off = i - 65536; }
    else                { src = w2;  off = i - 98304; }
    float4 a = *(const float4*)&src[off];
    f16x4 h = {(_Float16)a.x, (_Float16)a.y, (_Float16)a.z, (_Float16)a.w};
    *(f16x4*)&dst[i] = h;
}

// ---------------------------------------------------------------------------
// Fused q/k/v projections. X is fp32 NCHW; staged to f16 k-major LDS once
// (coalesced float4 reads, vectorized f16x4 LDS writes, ~2-way banks).
// MFMA 16x16x32 f16: A = X^T (rows = pixels), B = W^T (cols = out-ch).
// q,k stored f16 NHWC (for fdot2 in attn); v stored fp32 NHWC (for PV fma).
// grid (HW/64, 6, Nn), block 128: y>>1 = tensor, (y&1)*64 = oc half.
// ---------------------------------------------------------------------------
__global__ void __launch_bounds__(128)
qkv_k(const float* __restrict__ Xq, const float* __restrict__ Xk,
      const float* __restrict__ Xv, const _Float16* __restrict__ w16,
      _Float16* __restrict__ q16, _Float16* __restrict__ k16,
      float* __restrict__ v32)
{
    const int t   = blockIdx.y >> 1;
    const int oc0 = (blockIdx.y & 1) * 64;
    const int p0  = blockIdx.x * 64;
    const int z   = blockIdx.z;
    const float* X = (t == 0) ? Xq : (t == 1) ? Xk : Xv;
    const _Float16* W = w16 + (size_t)t * 16384;

    __shared__ _Float16 xl[128][72];   // [k][px], stride 72 halves
    const int tid = threadIdx.x;
    {
        const int px4 = (tid & 15) * 4, kg = tid >> 4;
        const float* Xz = X + (size_t)z * Cc * HW + p0 + px4;
#pragma unroll
        for (int kk = 0; kk < 16; ++kk) {
            const int k = kk * 8 + kg;
            float4 a = *(const float4*)&Xz[(size_t)k * HW];
            f16x4 h = {(_Float16)a.x, (_Float16)a.y, (_Float16)a.z, (_Float16)a.w};
            *(f16x4*)&xl[k][px4] = h;
        }
    }
    __syncthreads();

    const int w = tid >> 6, lane = tid & 63;
    const int n16 = lane & 15, quad = lane >> 4;
    const int pw = w * 32;

    f32x4 acc[2][4];
#pragma unroll
    for (int mi = 0; mi < 2; ++mi)
#pragma unroll
        for (int ni = 0; ni < 4; ++ni) acc[mi][ni] = (f32x4)0.f;

#pragma unroll
    for (int kc = 0; kc < 128; kc += 32) {
        f16x8 A[2], B[4];
#pragma unroll
        for (int mi = 0; mi < 2; ++mi) {
            const int px = pw + mi * 16 + n16;
            f16x8 av;
#pragma unroll
            for (int j = 0; j < 8; ++j) av[j] = xl[kc + quad * 8 + j][px];
            A[mi] = av;
        }
#pragma unroll
        for (int ni = 0; ni < 4; ++ni)
            B[ni] = *(const f16x8*)&W[(size_t)(oc0 + ni * 16 + n16) * 128 + kc + quad * 8];
#pragma unroll
        for (int mi = 0; mi < 2; ++mi)
#pragma unroll
            for (int ni = 0; ni < 4; ++ni)
                acc[mi][ni] = __builtin_amdgcn_mfma_f32_16x16x32_f16(
                    A[mi], B[ni], acc[mi][ni], 0, 0, 0);
    }

#pragma unroll
    for (int mi = 0; mi < 2; ++mi)
#pragma unroll
        for (int r = 0; r < 4; ++r) {
            const int pix = p0 + pw + mi * 16 + quad * 4 + r;
            const size_t base = ((size_t)z * HW + pix) * Cc + oc0;
            if (t == 0) {
#pragma unroll
                for (int ni = 0; ni < 4; ++ni)
                    q16[base + ni * 16 + n16] = (_Float16)acc[mi][ni][r];
            } else if (t == 1) {
#pragma unroll
                for (int ni = 0; ni < 4; ++ni)
                    k16[base + ni * 16 + n16] = (_Float16)acc[mi][ni][r];
            } else {
#pragma unroll
                for (int ni = 0; ni < 4; ++ni)
                    v32[base + ni * 16 + n16] = acc[mi][ni][r];
            }
        }
}

// ---------------------------------------------------------------------------
// Staging-free f16 MFMA GEMM over NHWC tensors.
// Y[z][pix][oc] = sum_k X[z][pix][k] * W[oc][k]; fragments loaded straight
// from global (8 consecutive k per lane). Block 128 thr = 2 waves, each
// 32 px x 64 oc. Optional bias/lrelu/resid(f16, 128ch)/sum&sumsq reduce.
// ---------------------------------------------------------------------------
template<int KT, bool OUTF16, bool BIAS, bool LRELU, bool RESID, bool REDUCE>
__global__ void __launch_bounds__(128)
mg_k(const _Float16* __restrict__ X, const _Float16* __restrict__ W,
     const float* __restrict__ bias, const _Float16* __restrict__ resid,
     void* __restrict__ Yv, float* __restrict__ sums, const int Mtot)
{
    const int z = blockIdx.z, oc0 = blockIdx.y * 64, p0 = blockIdx.x * 64;
    const int tid = threadIdx.x, w = tid >> 6, lane = tid & 63;
    const int n16 = lane & 15, quad = lane >> 4;
    const _Float16* Xz = X + ((size_t)z * HW + p0 + w * 32) * KT;

    f32x4 acc[2][4];
#pragma unroll
    for (int mi = 0; mi < 2; ++mi)
#pragma unroll
        for (int ni = 0; ni < 4; ++ni) acc[mi][ni] = (f32x4)0.f;

#pragma unroll
    for (int kc = 0; kc < KT; kc += 32) {
        f16x8 A[2], B[4];
#pragma unroll
        for (int mi = 0; mi < 2; ++mi)
            A[mi] = *(const f16x8*)&Xz[(size_t)(mi * 16 + n16) * KT + kc + quad * 8];
#pragma unroll
        for (int ni = 0; ni < 4; ++ni)
            B[ni] = *(const f16x8*)&W[(size_t)(oc0 + ni * 16 + n16) * KT + kc + quad * 8];
#pragma unroll
        for (int mi = 0; mi < 2; ++mi)
#pragma unroll
            for (int ni = 0; ni < 4; ++ni)
                acc[mi][ni] = __builtin_amdgcn_mfma_f32_16x16x32_f16(
                    A[mi], B[ni], acc[mi][ni], 0, 0, 0);
    }

    float bv[4];
#pragma unroll
    for (int ni = 0; ni < 4; ++ni) bv[ni] = BIAS ? bias[oc0 + ni * 16 + n16] : 0.f;

    float lsum = 0.f, lsq = 0.f;
#pragma unroll
    for (int mi = 0; mi < 2; ++mi)
#pragma unroll
        for (int r = 0; r < 4; ++r) {
            const int pix = p0 + w * 32 + mi * 16 + quad * 4 + r;
            const size_t ob = ((size_t)z * HW + pix) * (size_t)Mtot + oc0;
            const size_t rb = ((size_t)z * HW + pix) * 128 + oc0;
#pragma unroll
            for (int ni = 0; ni < 4; ++ni) {
                float tv = acc[mi][ni][r] + bv[ni];
                if (LRELU) tv = tv >= 0.f ? tv : 0.2f * tv;
                if (RESID) tv += (float)resid[rb + ni * 16 + n16];
                if (REDUCE) { lsum += tv; lsq += tv * tv; }
                if (OUTF16) ((_Float16*)Yv)[ob + ni * 16 + n16] = (_Float16)tv;
                else        ((float*)Yv)[ob + ni * 16 + n16] = tv;
            }
        }

    if (REDUCE) {
#pragma unroll
        for (int m = 1; m < 64; m <<= 1) {
            lsum += __shfl_xor(lsum, m, 64);
            lsq  += __shfl_xor(lsq,  m, 64);
        }
        if (lane == 0) {
            atomicAdd(&sums[z * 2 + 0], lsum);
            atomicAdd(&sums[z * 2 + 1], lsq);
        }
    }
}

// ---------------------------------------------------------------------------
// Deformable window attention, 4 pixels per wave (16 lanes/pixel, 8 ch/lane).
// q,k f16 NHWC (QK via v_dot2_f32_f16); v fp32 NHWC (plain fma PV).
// All 25 samples share bilinear weights; corners live in a 6x6 patch.
// Logits combined from per-lane partials (linear), 1-round pair reduce,
// softmax 1/s folded into final scale. Wave-uniform interior fast path.
// ---------------------------------------------------------------------------
__global__ void __launch_bounds__(256)
attn_k(const _Float16* __restrict__ q, const _Float16* __restrict__ k,
       const float* __restrict__ v, const float* __restrict__ df,
       _Float16* __restrict__ out)
{
    const int blk = blockIdx.x;
    const int sw = (blk & 7) * (1152 / 8) + (blk >> 3);   // XCD band swizzle
    const int wv = sw * 4 + (threadIdx.x >> 6);
    const int lane = threadIdx.x & 63;
    const int gp = wv * 4 + (lane >> 4);                  // global pixel
    const int b = gp / HW;
    const int pix = gp - b * HW;
    const int y = pix / Ww, x = pix - y * Ww;
    const int co = (lane & 15) * 8;                       // channel offset

    const float dx = df[((size_t)b * 2 + 0) * HW + pix];
    const float dy = df[((size_t)b * 2 + 1) * HW + pix];
    const float flx = floorf(dx), fly = floorf(dy);
    const int bx = x - 2 + (int)flx;
    const int by = y - 2 + (int)fly;
    const float wx1 = dx - flx, wx0 = 1.f - wx1;
    const float wy1 = dy - fly, wy0 = 1.f - wy1;
    const float u00 = wy0 * wx0, u01 = wy0 * wx1, u10 = wy1 * wx0, u11 = wy1 * wx1;
    const float s00 = u00 * 0.25f, s01 = u01 * 0.25f,    // 1/sqrt(d_k) folded
                s10 = u10 * 0.25f, s11 = u11 * 0.25f;

    const f16x8 qv8 = *(const f16x8*)&q[((size_t)b * HW + pix) * Cc + co];
    const f16x2 q0 = {qv8[0], qv8[1]}, q1 = {qv8[2], qv8[3]},
                q2 = {qv8[4], qv8[5]}, q3 = {qv8[6], qv8[7]};

    const _Float16* kp = k + ((size_t)b * HW) * Cc + co;
    const float*    vp = v + ((size_t)b * HW) * Cc + co;

    const bool inb = (bx >= 0) & (by >= 0) & (bx <= Ww - 6) & (by <= Hh - 6);
    const int allin = __all(inb);

    float qk[36];
    if (allin) {
        const _Float16* kr = kp + (size_t)(by * Ww + bx) * Cc;
#pragma unroll
        for (int r = 0; r < 6; ++r) {
#pragma unroll
            for (int c = 0; c < 6; ++c) {
                const f16x8 kv = *(const f16x8*)&kr[c * Cc];
                f16x2 k0 = {kv[0], kv[1]}, k1 = {kv[2], kv[3]};
                f16x2 k2 = {kv[4], kv[5]}, k3 = {kv[6], kv[7]};
                float d = fdot2(q0, k0, 0.f);
                d = fdot2(q1, k1, d);
                d = fdot2(q2, k2, d);
                d = fdot2(q3, k3, d);
                qk[r * 6 + c] = d;
            }
            kr += Ww * Cc;
        }
    } else {
#pragma unroll
        for (int r = 0; r < 6; ++r) {
            const int yr = by + r;
            const bool rv = (yr >= 0) & (yr < Hh);
            const int yc = min(max(yr, 0), Hh - 1);
            const _Float16* kr = kp + (size_t)(yc * Ww) * Cc;
#pragma unroll
            for (int c = 0; c < 6; ++c) {
                const int xc = bx + c;
                const bool cv = rv & (xc >= 0) & (xc < Ww);
                const int xcc = min(max(xc, 0), Ww - 1);
                const f16x8 kv = *(const f16x8*)&kr[xcc * Cc];
                f16x2 k0 = {kv[0], kv[1]}, k1 = {kv[2], kv[3]};
                f16x2 k2 = {kv[4], kv[5]}, k3 = {kv[6], kv[7]};
                float d = fdot2(q0, k0, 0.f);
                d = fdot2(q1, k1, d);
                d = fdot2(q2, k2, d);
                d = fdot2(q3, k3, d);
                qk[r * 6 + c] = cv ? d : 0.f;
            }
        }
    }

    // logits from per-lane partials (tap combine is linear)
    float a[25];
#pragma unroll
    for (int py = 0; py < 5; ++py)
#pragma unroll
        for (int px = 0; px < 5; ++px) {
            float tv = s00 * qk[py * 6 + px];
            tv = fmaf(s01, qk[py * 6 + px + 1], tv);
            tv = fmaf(s10, qk[(py + 1) * 6 + px], tv);
            tv = fmaf(s11, qk[(py + 1) * 6 + px + 1], tv);
            a[py * 5 + px] = tv;
        }
    // single-round reduce over the head's slot pair
#pragma unroll
    for (int i = 0; i < 25; ++i) a[i] += __shfl_xor(a[i], 1, 64);

    float mx = a[0];
#pragma unroll
    for (int i = 1; i < 25; ++i) mx = fmaxf(mx, a[i]);
    float ssum = 0.f;
#pragma unroll
    for (int i = 0; i < 25; ++i) { a[i] = __expf(a[i] - mx); ssum += a[i]; }
    const float inv = 1.f / ssum;

    // spread attn (unnormalized) into 6x6 tap-weight field
    float wsum[36];
#pragma unroll
    for (int i = 0; i < 36; ++i) wsum[i] = 0.f;
#pragma unroll
    for (int py = 0; py < 5; ++py)
#pragma unroll
        for (int px = 0; px < 5; ++px) {
            const float av = a[py * 5 + px];
            wsum[py * 6 + px]           = fmaf(av, u00, wsum[py * 6 + px]);
            wsum[py * 6 + px + 1]       = fmaf(av, u01, wsum[py * 6 + px + 1]);
            wsum[(py + 1) * 6 + px]     = fmaf(av, u10, wsum[(py + 1) * 6 + px]);
            wsum[(py + 1) * 6 + px + 1] = fmaf(av, u11, wsum[(py + 1) * 6 + px + 1]);
        }

    float o[8] = {0.f, 0.f, 0.f, 0.f, 0.f, 0.f, 0.f, 0.f};
    if (allin) {
        const float* vr = vp + (size_t)(by * Ww + bx) * Cc;
#pragma unroll
        for (int r = 0; r < 6; ++r) {
#pragma unroll
            for (int c = 0; c < 6; ++c) {
                const float4 va = *(const float4*)&vr[c * Cc];
                const float4 vb = *(const float4*)&vr[c * Cc + 4];
                const float wgt = wsum[r * 6 + c];
                o[0] = fmaf(wgt, va.x, o[0]); o[1] = fmaf(wgt, va.y, o[1]);
                o[2] = fmaf(wgt, va.z, o[2]); o[3] = fmaf(wgt, va.w, o[3]);
                o[4] = fmaf(wgt, vb.x, o[4]); o[5] = fmaf(wgt, vb.y, o[5]);
                o[6] = fmaf(wgt, vb.z, o[6]); o[7] = fmaf(wgt, vb.w, o[7]);
            }
            vr += Ww * Cc;
        }
    } else {
#pragma unroll
        for (int r = 0; r < 6; ++r) {
            const int yr = by + r;
            const bool rv = (yr >= 0) & (yr < Hh);
            const int yc = min(max(yr, 0), Hh - 1);
            const float* vr = vp + (size_t)(yc * Ww) * Cc;
#pragma unroll
            for (int c = 0; c < 6; ++c) {
                const int xc = bx + c;
                const bool cv = rv & (xc >= 0) & (xc < Ww);
                const int xcc = min(max(xc, 0), Ww - 1);
                const float4 va = *(const float4*)&vr[xcc * Cc];
                const float4 vb = *(const float4*)&vr[xcc * Cc + 4];
                const float wgt = cv ? wsum[r * 6 + c] : 0.f;
                o[0] = fmaf(wgt, va.x, o[0]); o[1] = fmaf(wgt, va.y, o[1]);
                o[2] = fmaf(wgt, va.z, o[2]); o[3] = fmaf(wgt, va.w, o[3]);
                o[4] = fmaf(wgt, vb.x, o[4]); o[5] = fmaf(wgt, vb.y, o[5]);
                o[6] = fmaf(wgt, vb.z, o[6]); o[7] = fmaf(wgt, vb.w, o[7]);
            }
        }
    }

    f16x8 ov;
#pragma unroll
    for (int j = 0; j < 8; ++j) ov[j] = (_Float16)(o[j] * inv);
    *(f16x8*)&out[((size_t)b * HW + pix) * Cc + co] = ov;
}

// ---------------------------------------------------------------------------
// GroupNorm finalize + NHWC fp32 -> NCHW fp32 transpose (LDS tile).
// grid (HW/64, Cc/32, Nn), block 256.
// ---------------------------------------------------------------------------
__global__ void __launch_bounds__(256)
gn_k(const float* __restrict__ y2, const float* __restrict__ sums,
     const float* __restrict__ gamma, const float* __restrict__ beta,
     float* __restrict__ out)
{
    __shared__ float t[32][68];
    const int z = blockIdx.z, c0 = blockIdx.y * 32, p0 = blockIdx.x * 64;
    const float invN = 1.f / (float)(Cc * HW);
    const float mean = sums[z * 2] * invN;
    const float var  = fmaf(-mean, mean, sums[z * 2 + 1] * invN);
    const float rs = rsqrtf(var + 1e-5f);
    const int tid = threadIdx.x;
    {
        const int px = tid >> 2, cq = tid & 3;
        const float* src = &y2[((size_t)z * HW + p0 + px) * Cc + c0 + cq * 8];
        const float4 a = *(const float4*)src;
        const float4 bq = *(const float4*)(src + 4);
        t[cq * 8 + 0][px] = a.x;  t[cq * 8 + 1][px] = a.y;
        t[cq * 8 + 2][px] = a.z;  t[cq * 8 + 3][px] = a.w;
        t[cq * 8 + 4][px] = bq.x; t[cq * 8 + 5][px] = bq.y;
        t[cq * 8 + 6][px] = bq.z; t[cq * 8 + 7][px] = bq.w;
    }
    __syncthreads();
    {
        const int c = tid >> 3, pq = tid & 7;
        const float g = gamma[c0 + c] * rs, be = beta[c0 + c];
        float4 o1, o2;
        o1.x = fmaf(t[c][pq * 8 + 0] - mean, g, be);
        o1.y = fmaf(t[c][pq * 8 + 1] - mean, g, be);
        o1.z = fmaf(t[c][pq * 8 + 2] - mean, g, be);
        o1.w = fmaf(t[c][pq * 8 + 3] - mean, g, be);
        o2.x = fmaf(t[c][pq * 8 + 4] - mean, g, be);
        o2.y = fmaf(t[c][pq * 8 + 5] - mean, g, be);
        o2.z = fmaf(t[c][pq * 8 + 6] - mean, g, be);
        o2.w = fmaf(t[c][pq * 8 + 7] - mean, g, be);
        float* dst = &out[((size_t)z * Cc + c0 + c) * HW + p0 + pq * 8];
        *(float4*)dst = o1;
        *(float4*)(dst + 4) = o2;
    }
}

// ---------------------------------------------------------------------------
extern "C" void kernel_launch(void* const* d_in, const int* in_sizes, int n_in,
                              void* d_out, int out_size, void* d_ws, size_t ws_size,
                              hipStream_t stream)
{
    const float* query  = (const float*)d_in[0];
    const float* key    = (const float*)d_in[1];
    const float* value  = (const float*)d_in[2];
    const float* deform = (const float*)d_in[3];
    const float* w_q    = (const float*)d_in[4];
    const float* w_k    = (const float*)d_in[5];
    const float* w_v    = (const float*)d_in[6];
    const float* w_fc   = (const float*)d_in[7];
    const float* mlp_w1 = (const float*)d_in[8];
    const float* mlp_b1 = (const float*)d_in[9];
    const float* mlp_w2 = (const float*)d_in[10];
    const float* mlp_b2 = (const float*)d_in[11];
    const float* gn_g   = (const float*)d_in[12];
    const float* gn_b   = (const float*)d_in[13];
    float* out = (float*)d_out;

    // workspace layout (28.8 MB total)
    char* wsb = (char*)d_ws;
    _Float16* w16 = (_Float16*)wsb;                  // 131072 halves
    float* sums = (float*)(wsb + 262144);            // 4 floats
    _Float16* T = (_Float16*)(wsb + 524288);
    const size_t S16 = (size_t)Nn * HW * Cc;         // halves per f16 tensor
    _Float16* q16  = T;                              // R0
    _Float16* k16  = T + S16;                        // R1
    float*    v32  = (float*)(T + 2 * S16);          // R2+R3
    _Float16* at16 = T + 4 * S16;                    // R4
    _Float16* y1   = T + 5 * S16;                    // R5
    _Float16* hb   = T;                              // R0+R1 (q,k dead)
    float*    y2   = v32;                            // R2+R3 (v dead)

    (void)hipMemsetAsync(sums, 0, 4 * sizeof(float), stream);

    // weights -> f16
    wcvt_k<<<dim3(128), dim3(256), 0, stream>>>(
        w_q, w_k, w_v, w_fc, mlp_w1, mlp_w2, w16);

    // fused q/k/v projections (q,k f16 NHWC; v fp32 NHWC)
    qkv_k<<<dim3(HW / 64, 6, Nn), dim3(128), 0, stream>>>(
        query, key, value, w16, q16, k16, v32);

    // deformable window attention -> f16 NHWC
    attn_k<<<dim3(Nn * HW / 16), dim3(256), 0, stream>>>(
        q16, k16, v32, deform, at16);

    // fc: y1 = w_fc @ attn_out
    mg_k<128, true, false, false, false, false>
        <<<dim3(HW / 64, 2, Nn), dim3(128), 0, stream>>>(
        at16, w16 + 49152, nullptr, nullptr, y1, nullptr, 128);

    // mlp hidden: h = lrelu(w1 @ y1 + b1)
    mg_k<128, true, true, true, false, false>
        <<<dim3(HW / 64, 4, Nn), dim3(128), 0, stream>>>(
        y1, w16 + 65536, mlp_b1, nullptr, hb, nullptr, 256);

    // y2 = y1 + w2 @ h + b2 (fp32 NHWC) + per-batch sum/sumsq
    mg_k<256, false, true, false, true, true>
        <<<dim3(HW / 64, 2, Nn), dim3(128), 0, stream>>>(
        hb, w16 + 98304, mlp_b2, y1, y2, sums, 128);

    // GroupNorm finalize + NHWC->NCHW
    gn_k<<<dim3(HW / 64, Cc / 32, Nn), dim3(256), 0, stream>>>(
        y2, sums, gn_g, gn_b, out);
}

// Round 6
// 193.135 us; speedup vs baseline: 1.0212x; 1.0212x over previous
//
#include <hip/hip_runtime.h>
#include <cstddef>

// Problem constants (n=2, c=128, h=w=96, hid=256, P=5, heads=8, d_k=16)
constexpr int Cc = 128;
constexpr int Hh = 96;
constexpr int Ww = 96;
constexpr int HW = Hh * Ww;      // 9216 pixels per image
constexpr int Nn = 2;

typedef __attribute__((ext_vector_type(2))) _Float16 f16x2;
typedef __attribute__((ext_vector_type(4))) _Float16 f16x4;
typedef __attribute__((ext_vector_type(8))) _Float16 f16x8;
typedef __attribute__((ext_vector_type(4))) float f32x4;

__device__ __forceinline__ float fdot2(f16x2 a, f16x2 b, float c) {
#if defined(__has_builtin) && __has_builtin(__builtin_amdgcn_fdot2)
    return __builtin_amdgcn_fdot2(a, b, c, false);
#else
    return (float)a[0] * (float)b[0] + (float)a[1] * (float)b[1] + c;
#endif
}

// ---------------------------------------------------------------------------
// Weight fp32 -> f16 (all 6 matrices into one packed buffer).
// wq @0, wk @16384, wv @32768, wfc @49152, w1 @65536, w2 @98304.
// ---------------------------------------------------------------------------
__global__ void __launch_bounds__(256)
wcvt_k(const float* __restrict__ wq, const float* __restrict__ wk,
       const float* __restrict__ wv, const float* __restrict__ wfc,
       const float* __restrict__ w1, const float* __restrict__ w2,
       _Float16* __restrict__ dst)
{
    const int i = (blockIdx.x * 256 + threadIdx.x) * 4;
    const float* src; int off;
    if (i < 16384)      { src = wq;  off = i; }
    else if (i < 32768) { src = wk;  off = i - 16384; }
    else if (i < 49152) { src = wv;  off = i - 32768; }
    else if (i < 65536) { src = wfc; off = i - 49152; }
    else if (i < 98304) { src = w1;  off = i - 65536; }
    else                { src = w2;  off = i - 98304; }
    float4 a = *(const float4*)&src[off];
    f16x4 h = {(_Float16)a.x, (_Float16)a.y, (_Float16)a.z, (_Float16)a.w};
    *(f16x4*)&dst[i] = h;
}

// ---------------------------------------------------------------------------
// Fused q/k/v projections. X fp32 NCHW staged once to f16 k-major LDS;
// both 64-oc halves computed from the same tile (halves X global traffic).
// MFMA 16x16x32 f16: A = X^T (rows = pixels), B = W^T (cols = out-ch).
// q,k f16 NHWC; v fp32 NHWC. grid (HW/64, 3, Nn), block 128.
// ---------------------------------------------------------------------------
__global__ void __launch_bounds__(128)
qkv_k(const float* __restrict__ Xq, const float* __restrict__ Xk,
      const float* __restrict__ Xv, const _Float16* __restrict__ w16,
      _Float16* __restrict__ q16, _Float16* __restrict__ k16,
      float* __restrict__ v32)
{
    const int t  = blockIdx.y;
    const int p0 = blockIdx.x * 64;
    const int z  = blockIdx.z;
    const float* X = (t == 0) ? Xq : (t == 1) ? Xk : Xv;
    const _Float16* W = w16 + (size_t)t * 16384;

    __shared__ _Float16 xl[128][72];   // [k][px]
    const int tid = threadIdx.x;
    {
        const int px4 = (tid & 15) * 4, kg = tid >> 4;
        const float* Xz = X + (size_t)z * Cc * HW + p0 + px4;
#pragma unroll
        for (int kk = 0; kk < 16; ++kk) {
            const int k = kk * 8 + kg;
            float4 a = *(const float4*)&Xz[(size_t)k * HW];
            f16x4 h = {(_Float16)a.x, (_Float16)a.y, (_Float16)a.z, (_Float16)a.w};
            *(f16x4*)&xl[k][px4] = h;
        }
    }
    __syncthreads();

    const int w = tid >> 6, lane = tid & 63;
    const int n16 = lane & 15, quad = lane >> 4;
    const int pw = w * 32;

#pragma unroll
    for (int half = 0; half < 2; ++half) {
        const int oc0 = half * 64;
        f32x4 acc[2][4];
#pragma unroll
        for (int mi = 0; mi < 2; ++mi)
#pragma unroll
            for (int ni = 0; ni < 4; ++ni) acc[mi][ni] = (f32x4)0.f;

#pragma unroll
        for (int kc = 0; kc < 128; kc += 32) {
            f16x8 A[2], B[4];
#pragma unroll
            for (int mi = 0; mi < 2; ++mi) {
                const int px = pw + mi * 16 + n16;
                f16x8 av;
#pragma unroll
                for (int j = 0; j < 8; ++j) av[j] = xl[kc + quad * 8 + j][px];
                A[mi] = av;
            }
#pragma unroll
            for (int ni = 0; ni < 4; ++ni)
                B[ni] = *(const f16x8*)&W[(size_t)(oc0 + ni * 16 + n16) * 128 + kc + quad * 8];
#pragma unroll
            for (int mi = 0; mi < 2; ++mi)
#pragma unroll
                for (int ni = 0; ni < 4; ++ni)
                    acc[mi][ni] = __builtin_amdgcn_mfma_f32_16x16x32_f16(
                        A[mi], B[ni], acc[mi][ni], 0, 0, 0);
        }

#pragma unroll
        for (int mi = 0; mi < 2; ++mi)
#pragma unroll
            for (int r = 0; r < 4; ++r) {
                const int pix = p0 + pw + mi * 16 + quad * 4 + r;
                const size_t base = ((size_t)z * HW + pix) * Cc + oc0;
                if (t == 0) {
#pragma unroll
                    for (int ni = 0; ni < 4; ++ni)
                        q16[base + ni * 16 + n16] = (_Float16)acc[mi][ni][r];
                } else if (t == 1) {
#pragma unroll
                    for (int ni = 0; ni < 4; ++ni)
                        k16[base + ni * 16 + n16] = (_Float16)acc[mi][ni][r];
                } else {
#pragma unroll
                    for (int ni = 0; ni < 4; ++ni)
                        v32[base + ni * 16 + n16] = acc[mi][ni][r];
                }
            }
    }
}

// ---------------------------------------------------------------------------
// Deformable window attention, 4 pixels per wave (16 lanes/pixel, 8 ch/lane).
// q,k f16 NHWC (QK via v_dot2_f32_f16); v fp32 NHWC (plain fma PV).
// All 25 samples share bilinear weights; corners live in a 6x6 patch.
// ---------------------------------------------------------------------------
__global__ void __launch_bounds__(256)
attn_k(const _Float16* __restrict__ q, const _Float16* __restrict__ k,
       const float* __restrict__ v, const float* __restrict__ df,
       _Float16* __restrict__ out)
{
    const int blk = blockIdx.x;
    const int sw = (blk & 7) * (1152 / 8) + (blk >> 3);   // XCD band swizzle
    const int wv = sw * 4 + (threadIdx.x >> 6);
    const int lane = threadIdx.x & 63;
    const int gp = wv * 4 + (lane >> 4);                  // global pixel
    const int b = gp / HW;
    const int pix = gp - b * HW;
    const int y = pix / Ww, x = pix - y * Ww;
    const int co = (lane & 15) * 8;                       // channel offset

    const float dx = df[((size_t)b * 2 + 0) * HW + pix];
    const float dy = df[((size_t)b * 2 + 1) * HW + pix];
    const float flx = floorf(dx), fly = floorf(dy);
    const int bx = x - 2 + (int)flx;
    const int by = y - 2 + (int)fly;
    const float wx1 = dx - flx, wx0 = 1.f - wx1;
    const float wy1 = dy - fly, wy0 = 1.f - wy1;
    const float u00 = wy0 * wx0, u01 = wy0 * wx1, u10 = wy1 * wx0, u11 = wy1 * wx1;
    const float s00 = u00 * 0.25f, s01 = u01 * 0.25f,
                s10 = u10 * 0.25f, s11 = u11 * 0.25f;

    const f16x8 qv8 = *(const f16x8*)&q[((size_t)b * HW + pix) * Cc + co];
    const f16x2 q0 = {qv8[0], qv8[1]}, q1 = {qv8[2], qv8[3]},
                q2 = {qv8[4], qv8[5]}, q3 = {qv8[6], qv8[7]};

    const _Float16* kp = k + ((size_t)b * HW) * Cc + co;
    const float*    vp = v + ((size_t)b * HW) * Cc + co;

    const bool inb = (bx >= 0) & (by >= 0) & (bx <= Ww - 6) & (by <= Hh - 6);
    const int allin = __all(inb);

    float qk[36];
    if (allin) {
        const _Float16* kr = kp + (size_t)(by * Ww + bx) * Cc;
#pragma unroll
        for (int r = 0; r < 6; ++r) {
#pragma unroll
            for (int c = 0; c < 6; ++c) {
                const f16x8 kv = *(const f16x8*)&kr[c * Cc];
                f16x2 k0 = {kv[0], kv[1]}, k1 = {kv[2], kv[3]};
                f16x2 k2 = {kv[4], kv[5]}, k3 = {kv[6], kv[7]};
                float d = fdot2(q0, k0, 0.f);
                d = fdot2(q1, k1, d);
                d = fdot2(q2, k2, d);
                d = fdot2(q3, k3, d);
                qk[r * 6 + c] = d;
            }
            kr += Ww * Cc;
        }
    } else {
#pragma unroll
        for (int r = 0; r < 6; ++r) {
            const int yr = by + r;
            const bool rv = (yr >= 0) & (yr < Hh);
            const int yc = min(max(yr, 0), Hh - 1);
            const _Float16* kr = kp + (size_t)(yc * Ww) * Cc;
#pragma unroll
            for (int c = 0; c < 6; ++c) {
                const int xc = bx + c;
                const bool cv = rv & (xc >= 0) & (xc < Ww);
                const int xcc = min(max(xc, 0), Ww - 1);
                const f16x8 kv = *(const f16x8*)&kr[xcc * Cc];
                f16x2 k0 = {kv[0], kv[1]}, k1 = {kv[2], kv[3]};
                f16x2 k2 = {kv[4], kv[5]}, k3 = {kv[6], kv[7]};
                float d = fdot2(q0, k0, 0.f);
                d = fdot2(q1, k1, d);
                d = fdot2(q2, k2, d);
                d = fdot2(q3, k3, d);
                qk[r * 6 + c] = cv ? d : 0.f;
            }
        }
    }

    float a[25];
#pragma unroll
    for (int py = 0; py < 5; ++py)
#pragma unroll
        for (int px = 0; px < 5; ++px) {
            float tv = s00 * qk[py * 6 + px];
            tv = fmaf(s01, qk[py * 6 + px + 1], tv);
            tv = fmaf(s10, qk[(py + 1) * 6 + px], tv);
            tv = fmaf(s11, qk[(py + 1) * 6 + px + 1], tv);
            a[py * 5 + px] = tv;
        }
#pragma unroll
    for (int i = 0; i < 25; ++i) a[i] += __shfl_xor(a[i], 1, 64);

    float mx = a[0];
#pragma unroll
    for (int i = 1; i < 25; ++i) mx = fmaxf(mx, a[i]);
    float ssum = 0.f;
#pragma unroll
    for (int i = 0; i < 25; ++i) { a[i] = __expf(a[i] - mx); ssum += a[i]; }
    const float inv = 1.f / ssum;

    float wsum[36];
#pragma unroll
    for (int i = 0; i < 36; ++i) wsum[i] = 0.f;
#pragma unroll
    for (int py = 0; py < 5; ++py)
#pragma unroll
        for (int px = 0; px < 5; ++px) {
            const float av = a[py * 5 + px];
            wsum[py * 6 + px]           = fmaf(av, u00, wsum[py * 6 + px]);
            wsum[py * 6 + px + 1]       = fmaf(av, u01, wsum[py * 6 + px + 1]);
            wsum[(py + 1) * 6 + px]     = fmaf(av, u10, wsum[(py + 1) * 6 + px]);
            wsum[(py + 1) * 6 + px + 1] = fmaf(av, u11, wsum[(py + 1) * 6 + px + 1]);
        }

    float o[8] = {0.f, 0.f, 0.f, 0.f, 0.f, 0.f, 0.f, 0.f};
    if (allin) {
        const float* vr = vp + (size_t)(by * Ww + bx) * Cc;
#pragma unroll
        for (int r = 0; r < 6; ++r) {
#pragma unroll
            for (int c = 0; c < 6; ++c) {
                const float4 va = *(const float4*)&vr[c * Cc];
                const float4 vb = *(const float4*)&vr[c * Cc + 4];
                const float wgt = wsum[r * 6 + c];
                o[0] = fmaf(wgt, va.x, o[0]); o[1] = fmaf(wgt, va.y, o[1]);
                o[2] = fmaf(wgt, va.z, o[2]); o[3] = fmaf(wgt, va.w, o[3]);
                o[4] = fmaf(wgt, vb.x, o[4]); o[5] = fmaf(wgt, vb.y, o[5]);
                o[6] = fmaf(wgt, vb.z, o[6]); o[7] = fmaf(wgt, vb.w, o[7]);
            }
            vr += Ww * Cc;
        }
    } else {
#pragma unroll
        for (int r = 0; r < 6; ++r) {
            const int yr = by + r;
            const bool rv = (yr >= 0) & (yr < Hh);
            const int yc = min(max(yr, 0), Hh - 1);
            const float* vr = vp + (size_t)(yc * Ww) * Cc;
#pragma unroll
            for (int c = 0; c < 6; ++c) {
                const int xc = bx + c;
                const bool cv = rv & (xc >= 0) & (xc < Ww);
                const int xcc = min(max(xc, 0), Ww - 1);
                const float4 va = *(const float4*)&vr[xcc * Cc];
                const float4 vb = *(const float4*)&vr[xcc * Cc + 4];
                const float wgt = cv ? wsum[r * 6 + c] : 0.f;
                o[0] = fmaf(wgt, va.x, o[0]); o[1] = fmaf(wgt, va.y, o[1]);
                o[2] = fmaf(wgt, va.z, o[2]); o[3] = fmaf(wgt, va.w, o[3]);
                o[4] = fmaf(wgt, vb.x, o[4]); o[5] = fmaf(wgt, vb.y, o[5]);
                o[6] = fmaf(wgt, vb.z, o[6]); o[7] = fmaf(wgt, vb.w, o[7]);
            }
        }
    }

    f16x8 ov;
#pragma unroll
    for (int j = 0; j < 8; ++j) ov[j] = (_Float16)(o[j] * inv);
    *(f16x8*)&out[((size_t)b * HW + pix) * Cc + co] = ov;
}

// ---------------------------------------------------------------------------
// Fused fc + MLP + residual + GN-reduction, one kernel.
// Per block (128 thr, 2 waves): 32 pixels carried through
//   y1 = wfc @ attn      (LDS, f16)
//   h  = lrelu(w1@y1+b1) (LDS, f16)
//   y2 = y1 + w2@h + b2  (global fp32 NHWC) + per-batch sum/sumsq atomics.
// Weights stream from L2. grid (HW/32, Nn).
// ---------------------------------------------------------------------------
__global__ void __launch_bounds__(128)
mlp_k(const _Float16* __restrict__ at, const _Float16* __restrict__ wfc,
      const _Float16* __restrict__ w1, const _Float16* __restrict__ w2,
      const float* __restrict__ b1, const float* __restrict__ b2,
      float* __restrict__ y2, float* __restrict__ sums)
{
    __shared__ _Float16 y1l[32][136];
    __shared__ _Float16 hl[32][264];

    const int z = blockIdx.y, p0 = blockIdx.x * 32;
    const int tid = threadIdx.x, w = tid >> 6, lane = tid & 63;
    const int n16 = lane & 15, quad = lane >> 4;
    const int pxw = w * 16;

    // ---- stage 1: y1 = at @ wfc^T ----
    {
        const _Float16* Az = at + ((size_t)z * HW + p0 + pxw) * 128;
        f32x4 acc[8];
#pragma unroll
        for (int ni = 0; ni < 8; ++ni) acc[ni] = (f32x4)0.f;
#pragma unroll
        for (int kc = 0; kc < 128; kc += 32) {
            const f16x8 A = *(const f16x8*)&Az[(size_t)n16 * 128 + kc + quad * 8];
#pragma unroll
            for (int ni = 0; ni < 8; ++ni) {
                const f16x8 B = *(const f16x8*)&wfc[(size_t)(ni * 16 + n16) * 128 + kc + quad * 8];
                acc[ni] = __builtin_amdgcn_mfma_f32_16x16x32_f16(A, B, acc[ni], 0, 0, 0);
            }
        }
#pragma unroll
        for (int ni = 0; ni < 8; ++ni)
#pragma unroll
            for (int r = 0; r < 4; ++r)
                y1l[pxw + quad * 4 + r][ni * 16 + n16] = (_Float16)acc[ni][r];
    }
    __syncthreads();

    // ---- stage 2: h = lrelu(w1 @ y1 + b1) ----
    {
        f32x4 acc[16];
#pragma unroll
        for (int ni = 0; ni < 16; ++ni) acc[ni] = (f32x4)0.f;
#pragma unroll
        for (int kc = 0; kc < 128; kc += 32) {
            const f16x8 A = *(const f16x8*)&y1l[pxw + n16][kc + quad * 8];
#pragma unroll
            for (int ni = 0; ni < 16; ++ni) {
                const f16x8 B = *(const f16x8*)&w1[(size_t)(ni * 16 + n16) * 128 + kc + quad * 8];
                acc[ni] = __builtin_amdgcn_mfma_f32_16x16x32_f16(A, B, acc[ni], 0, 0, 0);
            }
        }
#pragma unroll
        for (int ni = 0; ni < 16; ++ni) {
            const float bv = b1[ni * 16 + n16];
#pragma unroll
            for (int r = 0; r < 4; ++r) {
                float t = acc[ni][r] + bv;
                t = t >= 0.f ? t : 0.2f * t;
                hl[pxw + quad * 4 + r][ni * 16 + n16] = (_Float16)t;
            }
        }
    }
    __syncthreads();

    // ---- stage 3: y2 = y1 + w2 @ h + b2, reduce ----
    {
        f32x4 acc[8];
#pragma unroll
        for (int ni = 0; ni < 8; ++ni) acc[ni] = (f32x4)0.f;
#pragma unroll
        for (int kc = 0; kc < 256; kc += 32) {
            const f16x8 A = *(const f16x8*)&hl[pxw + n16][kc + quad * 8];
#pragma unroll
            for (int ni = 0; ni < 8; ++ni) {
                const f16x8 B = *(const f16x8*)&w2[(size_t)(ni * 16 + n16) * 256 + kc + quad * 8];
                acc[ni] = __builtin_amdgcn_mfma_f32_16x16x32_f16(A, B, acc[ni], 0, 0, 0);
            }
        }
        float lsum = 0.f, lsq = 0.f;
#pragma unroll
        for (int ni = 0; ni < 8; ++ni) {
            const float bv = b2[ni * 16 + n16];
#pragma unroll
            for (int r = 0; r < 4; ++r) {
                const int px = pxw + quad * 4 + r;
                float t = acc[ni][r] + bv + (float)y1l[px][ni * 16 + n16];
                lsum += t; lsq += t * t;
                y2[((size_t)z * HW + p0 + px) * 128 + ni * 16 + n16] = t;
            }
        }
#pragma unroll
        for (int m = 1; m < 64; m <<= 1) {
            lsum += __shfl_xor(lsum, m, 64);
            lsq  += __shfl_xor(lsq,  m, 64);
        }
        if (lane == 0) {
            atomicAdd(&sums[z * 2 + 0], lsum);
            atomicAdd(&sums[z * 2 + 1], lsq);
        }
    }
}

// ---------------------------------------------------------------------------
// GroupNorm finalize + NHWC fp32 -> NCHW fp32 transpose (LDS tile).
// ---------------------------------------------------------------------------
__global__ void __launch_bounds__(256)
gn_k(const float* __restrict__ y2, const float* __restrict__ sums,
     const float* __restrict__ gamma, const float* __restrict__ beta,
     float* __restrict__ out)
{
    __shared__ float t[32][68];
    const int z = blockIdx.z, c0 = blockIdx.y * 32, p0 = blockIdx.x * 64;
    const float invN = 1.f / (float)(Cc * HW);
    const float mean = sums[z * 2] * invN;
    const float var  = fmaf(-mean, mean, sums[z * 2 + 1] * invN);
    const float rs = rsqrtf(var + 1e-5f);
    const int tid = threadIdx.x;
    {
        const int px = tid >> 2, cq = tid & 3;
        const float* src = &y2[((size_t)z * HW + p0 + px) * Cc + c0 + cq * 8];
        const float4 a = *(const float4*)src;
        const float4 bq = *(const float4*)(src + 4);
        t[cq * 8 + 0][px] = a.x;  t[cq * 8 + 1][px] = a.y;
        t[cq * 8 + 2][px] = a.z;  t[cq * 8 + 3][px] = a.w;
        t[cq * 8 + 4][px] = bq.x; t[cq * 8 + 5][px] = bq.y;
        t[cq * 8 + 6][px] = bq.z; t[cq * 8 + 7][px] = bq.w;
    }
    __syncthreads();
    {
        const int c = tid >> 3, pq = tid & 7;
        const float g = gamma[c0 + c] * rs, be = beta[c0 + c];
        float4 o1, o2;
        o1.x = fmaf(t[c][pq * 8 + 0] - mean, g, be);
        o1.y = fmaf(t[c][pq * 8 + 1] - mean, g, be);
        o1.z = fmaf(t[c][pq * 8 + 2] - mean, g, be);
        o1.w = fmaf(t[c][pq * 8 + 3] - mean, g, be);
        o2.x = fmaf(t[c][pq * 8 + 4] - mean, g, be);
        o2.y = fmaf(t[c][pq * 8 + 5] - mean, g, be);
        o2.z = fmaf(t[c][pq * 8 + 6] - mean, g, be);
        o2.w = fmaf(t[c][pq * 8 + 7] - mean, g, be);
        float* dst = &out[((size_t)z * Cc + c0 + c) * HW + p0 + pq * 8];
        *(float4*)dst = o1;
        *(float4*)(dst + 4) = o2;
    }
}

// ---------------------------------------------------------------------------
extern "C" void kernel_launch(void* const* d_in, const int* in_sizes, int n_in,
                              void* d_out, int out_size, void* d_ws, size_t ws_size,
                              hipStream_t stream)
{
    const float* query  = (const float*)d_in[0];
    const float* key    = (const float*)d_in[1];
    const float* value  = (const float*)d_in[2];
    const float* deform = (const float*)d_in[3];
    const float* w_q    = (const float*)d_in[4];
    const float* w_k    = (const float*)d_in[5];
    const float* w_v    = (const float*)d_in[6];
    const float* w_fc   = (const float*)d_in[7];
    const float* mlp_w1 = (const float*)d_in[8];
    const float* mlp_b1 = (const float*)d_in[9];
    const float* mlp_w2 = (const float*)d_in[10];
    const float* mlp_b2 = (const float*)d_in[11];
    const float* gn_g   = (const float*)d_in[12];
    const float* gn_b   = (const float*)d_in[13];
    float* out = (float*)d_out;

    // workspace layout
    char* wsb = (char*)d_ws;
    _Float16* w16 = (_Float16*)wsb;                  // 131072 halves
    float* sums = (float*)(wsb + 262144);            // 4 floats
    _Float16* T = (_Float16*)(wsb + 524288);
    const size_t S16 = (size_t)Nn * HW * Cc;         // halves per f16 tensor
    _Float16* q16  = T;                              // R0
    _Float16* k16  = T + S16;                        // R1
    float*    v32  = (float*)(T + 2 * S16);          // R2+R3
    _Float16* at16 = T + 4 * S16;                    // R4
    float*    y2   = v32;                            // R2+R3 (v dead after attn)

    (void)hipMemsetAsync(sums, 0, 4 * sizeof(float), stream);

    // weights -> f16
    wcvt_k<<<dim3(128), dim3(256), 0, stream>>>(
        w_q, w_k, w_v, w_fc, mlp_w1, mlp_w2, w16);

    // fused q/k/v projections (q,k f16 NHWC; v fp32 NHWC)
    qkv_k<<<dim3(HW / 64, 3, Nn), dim3(128), 0, stream>>>(
        query, key, value, w16, q16, k16, v32);

    // deformable window attention -> f16 NHWC
    attn_k<<<dim3(Nn * HW / 16), dim3(256), 0, stream>>>(
        q16, k16, v32, deform, at16);

    // fused fc + MLP + residual + GN reduction
    mlp_k<<<dim3(HW / 32, Nn), dim3(128), 0, stream>>>(
        at16, w16 + 49152, w16 + 65536, w16 + 98304,
        mlp_b1, mlp_b2, y2, sums);

    // GroupNorm finalize + NHWC->NCHW
    gn_k<<<dim3(HW / 64, Cc / 32, Nn), dim3(256), 0, stream>>>(
        y2, sums, gn_g, gn_b, out);
}